// Round 4
// baseline (573.902 us; speedup 1.0000x reference)
//
#include <hip/hip_runtime.h>
#include <hip/hip_bf16.h>

// MLA forward, MI355X round 4: attn 2 blocks/CU (no vbuf, direct-global V),
// defer-max + setprio + exp2 softmax; consolidated launches (7 kernels).
// B=2 S=2048 D=2048 H=16 NOPE=128 ROPE=64 VH=128 QR=KVR=512

typedef __attribute__((ext_vector_type(8))) short s8v;   // 8 bf16 (4 VGPR)
typedef __attribute__((ext_vector_type(4))) float f4v;   // 4 fp32 acc

#define DEV static __device__ __forceinline__

DEV ushort f2b(float f) {
  __hip_bfloat16 h = __float2bfloat16(f);
  return *reinterpret_cast<ushort*>(&h);
}
DEV float b2f(ushort u) {
  __hip_bfloat16 h = *reinterpret_cast<__hip_bfloat16*>(&u);
  return __bfloat162float(h);
}
DEV f4v mfma16(s8v a, s8v b, f4v c) {
  return __builtin_amdgcn_mfma_f32_16x16x32_bf16(a, b, c, 0, 0, 0);
}
DEV void gload16(const ushort* g, ushort* l) {
  __builtin_amdgcn_global_load_lds((const __attribute__((address_space(1))) void*)g,
                                   (__attribute__((address_space(3))) void*)l, 16, 0, 0);
}

// ---------------------------------------------------------------- all casts, one launch
struct CastSeg { const float* src; ushort* dst; int n4; int blk0; };
struct CastTab { CastSeg seg[10]; };

__global__ __launch_bounds__(256) void cast_all_kernel(CastTab t) {
  int b = blockIdx.x;
  int si = 0;
#pragma unroll
  for (int i = 1; i < 10; ++i) si = (b >= t.seg[i].blk0) ? i : si;
  int i4 = (b - t.seg[si].blk0) * 256 + threadIdx.x;
  if (i4 >= t.seg[si].n4) return;
  ushort4 o;
  if (t.seg[si].src) {
    float4 v = reinterpret_cast<const float4*>(t.seg[si].src)[i4];
    o.x = f2b(v.x); o.y = f2b(v.y); o.z = f2b(v.z); o.w = f2b(v.w);
  } else {
    o = ushort4{0, 0, 0, 0};
  }
  reinterpret_cast<ushort4*>(t.seg[si].dst)[i4] = o;
}

// ---------------------------------------------------------------- GEMM C = A * B^T
// 128x128 tile, BK=32, global_load_lds dwordx4, double-buffered, 4 waves.
template <bool BF16OUT>
DEV void gemm_core(const ushort* __restrict__ A, const ushort* __restrict__ B,
                   void* __restrict__ C, int N, int K, int row0, int col0,
                   ushort* a_lds0, ushort* a_lds1, ushort* b_lds0, ushort* b_lds1) {
  const int tid = threadIdx.x;
  const int lane = tid & 63, wv = tid >> 6;
  const int wm = wv >> 1, wn = wv & 1;
  const int l15 = lane & 15, l4 = lane >> 4;
  const int srow = lane >> 2;
  const int scol = (lane & 3) * 8;
  ushort* a_lds[2] = {a_lds0, a_lds1};
  ushort* b_lds[2] = {b_lds0, b_lds1};

  f4v acc[4][4];
#pragma unroll
  for (int i = 0; i < 4; ++i)
#pragma unroll
    for (int j = 0; j < 4; ++j) acc[i][j] = f4v{0.f, 0.f, 0.f, 0.f};

  auto stage = [&](int k0, int bsel) {
#pragma unroll
    for (int i = 0; i < 2; ++i) {
      int s = wv * 2 + i;
      gload16(&A[(size_t)(row0 + s * 16 + srow) * K + k0 + scol], &a_lds[bsel][s * 512]);
      gload16(&B[(size_t)(col0 + s * 16 + srow) * K + k0 + scol], &b_lds[bsel][s * 512]);
    }
  };

  stage(0, 0);
  int cur = 0;
  for (int k0 = 0; k0 < K; k0 += 32) {
    __syncthreads();
    if (k0 + 32 < K) stage(k0 + 32, cur ^ 1);
    s8v af[4], bfr[4];
#pragma unroll
    for (int mi = 0; mi < 4; ++mi)
      af[mi] = *reinterpret_cast<const s8v*>(&a_lds[cur][(wm * 64 + mi * 16 + l15) * 32 + 8 * l4]);
#pragma unroll
    for (int ni = 0; ni < 4; ++ni)
      bfr[ni] = *reinterpret_cast<const s8v*>(&b_lds[cur][(wn * 64 + ni * 16 + l15) * 32 + 8 * l4]);
#pragma unroll
    for (int mi = 0; mi < 4; ++mi)
#pragma unroll
      for (int ni = 0; ni < 4; ++ni) acc[mi][ni] = mfma16(af[mi], bfr[ni], acc[mi][ni]);
    cur ^= 1;
  }

#pragma unroll
  for (int mi = 0; mi < 4; ++mi)
#pragma unroll
    for (int ni = 0; ni < 4; ++ni)
#pragma unroll
      for (int j = 0; j < 4; ++j) {
        int r = row0 + wm * 64 + mi * 16 + l4 * 4 + j;   // C/D: row=(lane>>4)*4+reg
        int cl = col0 + wn * 64 + ni * 16 + l15;          //      col=lane&15
        if (BF16OUT)
          reinterpret_cast<ushort*>(C)[(size_t)r * N + cl] = f2b(acc[mi][ni][j]);
        else
          reinterpret_cast<float*>(C)[(size_t)r * N + cl] = acc[mi][ni][j];
      }
}

template <bool BF16OUT>
__global__ __launch_bounds__(256) void gemm_bt(const ushort* __restrict__ A,
                                               const ushort* __restrict__ B,
                                               void* __restrict__ C, int N, int K) {
  __shared__ ushort a0[128 * 32], a1[128 * 32], b0[128 * 32], b1[128 * 32];
  gemm_core<BF16OUT>(A, B, C, N, K, blockIdx.x * 128, blockIdx.y * 128, a0, a1, b0, b1);
}

// Q-decompress (N=3072) and KV-decompress (N=4096) in one launch. K=512, M=4096.
__global__ __launch_bounds__(256) void gemm2_dual(const ushort* __restrict__ nq,
                                                  const ushort* __restrict__ w2q,
                                                  ushort* __restrict__ g2q,
                                                  const ushort* __restrict__ nkv,
                                                  const ushort* __restrict__ w2kv,
                                                  ushort* __restrict__ g2kv) {
  __shared__ ushort a0[128 * 32], a1[128 * 32], b0[128 * 32], b1[128 * 32];
  int by = blockIdx.y;
  if (by < 24)
    gemm_core<true>(nq, w2q, g2q, 3072, 512, blockIdx.x * 128, by * 128, a0, a1, b0, b1);
  else
    gemm_core<true>(nkv, w2kv, g2kv, 4096, 512, blockIdx.x * 128, (by - 24) * 128, a0, a1, b0, b1);
}

// ---------------------------------------------------------------- RMSNorm(cq,ckv) + RoPE(k_rope)
__global__ __launch_bounds__(256) void norm_rope1_kernel(
    const float* __restrict__ g1, const float* __restrict__ wq, const float* __restrict__ wkv,
    const float* __restrict__ freqs, ushort* __restrict__ nq, ushort* __restrict__ nkv,
    ushort* __restrict__ kro) {
  const int m = blockIdx.x;       // 0..4095 = b*2048+s
  const int s = m & 2047;
  const int tid = threadIdx.x;
  __shared__ float red[4];
  const float* row = g1 + (size_t)m * 1152;

  float v0 = row[tid], v1 = row[tid + 256];
  float ss = v0 * v0 + v1 * v1;
#pragma unroll
  for (int off = 32; off > 0; off >>= 1) ss += __shfl_down(ss, off);
  if ((tid & 63) == 0) red[tid >> 6] = ss;
  __syncthreads();
  float r = rsqrtf((red[0] + red[1] + red[2] + red[3]) * (1.0f / 512.0f) + 1e-6f);
  nq[(size_t)m * 512 + tid] = f2b(v0 * r * wq[tid]);
  nq[(size_t)m * 512 + tid + 256] = f2b(v1 * r * wq[tid + 256]);

  float u0 = row[512 + tid], u1 = row[512 + tid + 256];
  float ss2 = u0 * u0 + u1 * u1;
#pragma unroll
  for (int off = 32; off > 0; off >>= 1) ss2 += __shfl_down(ss2, off);
  __syncthreads();
  if ((tid & 63) == 0) red[tid >> 6] = ss2;
  __syncthreads();
  float r2 = rsqrtf((red[0] + red[1] + red[2] + red[3]) * (1.0f / 512.0f) + 1e-6f);
  nkv[(size_t)m * 512 + tid] = f2b(u0 * r2 * wkv[tid]);
  nkv[(size_t)m * 512 + tid + 256] = f2b(u1 * r2 * wkv[tid + 256]);

  if (tid < 32) {
    float x0 = row[1024 + 2 * tid], x1 = row[1024 + 2 * tid + 1];
    float c = freqs[s * 64 + 2 * tid], sn = freqs[s * 64 + 2 * tid + 1];
    kro[(size_t)m * 64 + 2 * tid] = f2b((x0 * c - x1 * sn) * (1.0f / 16.0f));
    kro[(size_t)m * 64 + 2 * tid + 1] = f2b((x0 * sn + x1 * c) * (1.0f / 16.0f));
  }
}

// ---------------------------------------------------------------- V transpose + Q RoPE, one launch
__global__ __launch_bounds__(256) void misc_fused_kernel(ushort* __restrict__ g2q,
                                                         const float* __restrict__ freqs,
                                                         const ushort* __restrict__ g2kv,
                                                         ushort* __restrict__ vT) {
  const int tid = threadIdx.x;
  if (blockIdx.x < 2048) {   // ---- V transpose: g2kv v-section -> vT (B,H,128,S)
    int blk = blockIdx.x;
    int bh = blk >> 6;
    int rem = blk & 63;
    int st = rem >> 1, dt = rem & 1;
    int b = bh >> 4, h = bh & 15;
    __shared__ ushort t[64][72];
#pragma unroll
    for (int it = 0; it < 2; ++it) {
      int c = tid + it * 256;
      int sl = c >> 3, cc = (c & 7) * 8;
      *reinterpret_cast<uint4*>(&t[sl][cc]) = *reinterpret_cast<const uint4*>(
          &g2kv[(size_t)(b * 2048 + st * 64 + sl) * 4096 + 2048 + h * 128 + dt * 64 + cc]);
    }
    __syncthreads();
#pragma unroll
    for (int it = 0; it < 2; ++it) {
      int c = tid + it * 256;
      int dl = c >> 3, cc = (c & 7) * 8;
      ushort tmp[8];
#pragma unroll
      for (int e = 0; e < 8; ++e) tmp[e] = t[cc + e][dl];
      *reinterpret_cast<uint4*>(&vT[(size_t)(bh * 128 + dt * 64 + dl) * 2048 + st * 64 + cc]) =
          *reinterpret_cast<uint4*>(tmp);
    }
  } else {                    // ---- RoPE on q_rope (in-place)
    int idx = (blockIdx.x - 2048) * 256 + tid;  // 4096*16*32
    int m = idx >> 9;
    int rem = idx & 511;
    int h = rem >> 5, j = rem & 31;
    int s = m & 2047;
    size_t base = (size_t)m * 3072 + 2048 + h * 64 + 2 * j;
    ushort2 pr = *reinterpret_cast<ushort2*>(&g2q[base]);
    float x0 = b2f(pr.x), x1 = b2f(pr.y);
    float c = freqs[s * 64 + 2 * j], sn = freqs[s * 64 + 2 * j + 1];
    ushort2 o;
    o.x = f2b(x0 * c - x1 * sn);
    o.y = f2b(x0 * sn + x1 * c);
    *reinterpret_cast<ushort2*>(&g2q[base]) = o;
  }
}

// ---------------------------------------------------------------- causal flash attention
// QBLK=128, 8 waves x 16 q-rows, KVBLK=64. K dbuf via global_load_lds (both-sides
// XOR swizzle); V fragments read directly from global (L2). LDS 66KB -> 2 blocks/CU.
__global__ __launch_bounds__(512, 4) void attn_kernel(const ushort* __restrict__ q,     // 4096x3072
                                                      const ushort* __restrict__ knope, // 4096x4096
                                                      const ushort* __restrict__ kro,   // 4096x64
                                                      const ushort* __restrict__ vT,    // (B*H*128)x2048
                                                      ushort* __restrict__ out) {       // 4096x2048
  const int lid = blockIdx.x;               // 512 blocks
  const int bh = lid & 31;
  const int qt = 15 - (lid >> 5);           // heavy-first (LPT)
  const int b = bh >> 4, h = bh & 15;
  const int tid = threadIdx.x, lane = tid & 63, w = tid >> 6;
  const int l15 = lane & 15, l4 = lane >> 4;

  __shared__ ushort kbuf[2][64 * 192];      // 24KB/buf, linear, swizzled
  __shared__ ushort p_lds[8][16][72];       // per-wave P (16q x 64k, +8 pad)

  s8v qf[6];
  {
    const size_t qbase = (size_t)(b * 2048 + qt * 128 + w * 16 + l15) * 3072;
#pragma unroll
    for (int kc = 0; kc < 4; ++kc)
      qf[kc] = *reinterpret_cast<const s8v*>(&q[qbase + h * 128 + kc * 32 + 8 * l4]);
#pragma unroll
    for (int kc = 4; kc < 6; ++kc)
      qf[kc] = *reinterpret_cast<const s8v*>(&q[qbase + 2048 + h * 64 + (kc - 4) * 32 + 8 * l4]);
  }

  f4v oacc[8];
#pragma unroll
  for (int i = 0; i < 8; ++i) oacc[i] = f4v{0.f, 0.f, 0.f, 0.f};
  float m_r[4] = {-INFINITY, -INFINITY, -INFINITY, -INFINITY};
  float l_r[4] = {0.f, 0.f, 0.f, 0.f};
  // softmax in exp2 space: s' = s * scale * log2(e)
  const float sc2 = 0.07216878364870323f * 1.44269504f;
  const int nkt = 2 * qt + 2;
  const int kbase = b * 2048;
  const ushort* vbh = vT + (size_t)bh * 128 * 2048;

  auto stage = [&](int kt, int bsel) {
    const int krow0 = kbase + kt * 64;
#pragma unroll
    for (int i = 0; i < 3; ++i) {           // K: 24 segs of 1KB, 3 per wave
      int s = w * 3 + i;
      int p = s * 1024 + lane * 16;
      int row = p / 384;
      int col = ((p ^ ((row & 7) << 4)) - row * 384) >> 1;
      const ushort* src = (col < 128)
          ? &knope[(size_t)(krow0 + row) * 4096 + h * 128 + col]
          : &kro[(size_t)(krow0 + row) * 64 + (col - 128)];
      gload16(src, &kbuf[bsel][s * 512]);
    }
  };

  stage(0, 0);
  int cur = 0;
  for (int kt = 0; kt < nkt; ++kt) {
    __syncthreads();
    if (kt + 1 < nkt) stage(kt + 1, cur ^ 1);
    const char* kb = (const char*)kbuf[cur];

    // S = Q K^T (16 q x 64 keys per wave)
    f4v sacc[4];
    __builtin_amdgcn_s_setprio(1);
#pragma unroll
    for (int nb = 0; nb < 4; ++nb) {
      sacc[nb] = f4v{0.f, 0.f, 0.f, 0.f};
      const int row = nb * 16 + l15;
      const int sw = (row & 7) << 4;
#pragma unroll
      for (int kc = 0; kc < 6; ++kc) {
        s8v bfr = *reinterpret_cast<const s8v*>(kb + row * 384 + ((kc * 64 + l4 * 16) ^ sw));
        sacc[nb] = mfma16(qf[kc], bfr, sacc[nb]);
      }
    }
    __builtin_amdgcn_s_setprio(0);

    // scale (exp2 space) + causal mask
    const int qrow0 = qt * 128 + w * 16 + l4 * 4;
#pragma unroll
    for (int nb = 0; nb < 4; ++nb) {
      int key = kt * 64 + nb * 16 + l15;
#pragma unroll
      for (int j = 0; j < 4; ++j) {
        float sv = sacc[nb][j] * sc2;
        if (kt >= 2 * qt && key > qrow0 + j) sv = -INFINITY;
        sacc[nb][j] = sv;
      }
    }
    // row max over 64 keys
    float mx[4];
#pragma unroll
    for (int j = 0; j < 4; ++j)
      mx[j] = fmaxf(fmaxf(sacc[0][j], sacc[1][j]), fmaxf(sacc[2][j], sacc[3][j]));
#pragma unroll
    for (int off = 1; off < 16; off <<= 1)
#pragma unroll
      for (int j = 0; j < 4; ++j) mx[j] = fmaxf(mx[j], __shfl_xor(mx[j], off));

    // T13 defer-max: skip rescale unless some row grew by > 8 (exp2 units)
    float need = fmaxf(fmaxf(mx[0] - m_r[0], mx[1] - m_r[1]),
                       fmaxf(mx[2] - m_r[2], mx[3] - m_r[3]));
    if (!__all(need <= 8.0f)) {
      float al[4];
#pragma unroll
      for (int j = 0; j < 4; ++j) {
        float mnew = fmaxf(m_r[j], mx[j]);
        al[j] = exp2f(m_r[j] - mnew);
        m_r[j] = mnew;
        l_r[j] *= al[j];
      }
#pragma unroll
      for (int nv = 0; nv < 8; ++nv)
#pragma unroll
        for (int j = 0; j < 4; ++j) oacc[nv][j] *= al[j];
    }
    // P = exp2(s' - m'), row-sums
    float rs[4] = {0.f, 0.f, 0.f, 0.f};
#pragma unroll
    for (int nb = 0; nb < 4; ++nb)
#pragma unroll
      for (int j = 0; j < 4; ++j) {
        float p = exp2f(sacc[nb][j] - m_r[j]);
        sacc[nb][j] = p;
        rs[j] += p;
      }
#pragma unroll
    for (int off = 1; off < 16; off <<= 1)
#pragma unroll
      for (int j = 0; j < 4; ++j) rs[j] += __shfl_xor(rs[j], off);
#pragma unroll
    for (int j = 0; j < 4; ++j) l_r[j] += rs[j];
    // P -> LDS (wave-private transpose to A-operand layout)
#pragma unroll
    for (int nb = 0; nb < 4; ++nb)
#pragma unroll
      for (int j = 0; j < 4; ++j)
        p_lds[w][l4 * 4 + j][nb * 16 + l15] = f2b(sacc[nb][j]);

    // O += P V, V fragments direct from global (L2-resident)
    const ushort* vbase = vbh + kt * 64;
    __builtin_amdgcn_s_setprio(1);
#pragma unroll 1
    for (int kc2 = 0; kc2 < 2; ++kc2) {
      s8v pf = *reinterpret_cast<const s8v*>(&p_lds[w][l15][kc2 * 32 + 8 * l4]);
      s8v vf[8];
#pragma unroll
      for (int nv = 0; nv < 8; ++nv)
        vf[nv] = *reinterpret_cast<const s8v*>(
            &vbase[(size_t)(nv * 16 + l15) * 2048 + kc2 * 32 + 8 * l4]);
#pragma unroll
      for (int nv = 0; nv < 8; ++nv) oacc[nv] = mfma16(pf, vf[nv], oacc[nv]);
    }
    __builtin_amdgcn_s_setprio(0);
    cur ^= 1;
  }

  // epilogue: normalize + store (B,S,H*128) bf16
#pragma unroll
  for (int j = 0; j < 4; ++j) {
    float inv = 1.0f / l_r[j];
    int m = b * 2048 + qt * 128 + w * 16 + l4 * 4 + j;
#pragma unroll
    for (int nv = 0; nv < 8; ++nv)
      out[(size_t)m * 2048 + h * 128 + nv * 16 + l15] = f2b(oacc[nv][j] * inv);
  }
}

// ---------------------------------------------------------------- launch
// Workspace layout (lifetime-aliased, peak 96.5 MiB):
//   [ 0,32M)  g2kv   overlay: g1 fp32 18M
//   [32,56M)  g2q    overlay: xbf 16M @32M, w1 4.5M @48M
//   [56,72M)  vT     overlay: nq 4M @56M, nkv 4M @60M, w2q 3M @64M, w2kv 4M @67M
//   [72,88M)  att
//   [88,96M)  wpj
//   [96,96.5M) kro
extern "C" void kernel_launch(void* const* d_in, const int* in_sizes, int n_in,
                              void* d_out, int out_size, void* d_ws, size_t ws_size,
                              hipStream_t stream) {
  const float* x       = (const float*)d_in[0];
  const float* freqs   = (const float*)d_in[2];
  const float* w_cq    = (const float*)d_in[3];
  const float* w_qnorm = (const float*)d_in[4];
  const float* w_dqn   = (const float*)d_in[5];
  const float* w_dqr   = (const float*)d_in[6];
  const float* w_ckv   = (const float*)d_in[7];
  const float* w_kvnorm= (const float*)d_in[8];
  const float* w_dkn   = (const float*)d_in[9];
  const float* w_dv    = (const float*)d_in[10];
  const float* w_krope = (const float*)d_in[11];
  const float* w_proj  = (const float*)d_in[12];
  float* out = (float*)d_out;

  char* ws = (char*)d_ws;
  const size_t MB = 1ull << 20;
  ushort* g2kv = (ushort*)(ws + 0);
  float*  g1   = (float*) (ws + 0);
  ushort* g2q  = (ushort*)(ws + 32 * MB);
  ushort* xbf  = (ushort*)(ws + 32 * MB);
  ushort* w1   = (ushort*)(ws + 48 * MB);
  ushort* vT   = (ushort*)(ws + 56 * MB);
  ushort* nq   = (ushort*)(ws + 56 * MB);
  ushort* nkv  = (ushort*)(ws + 60 * MB);
  ushort* w2q  = (ushort*)(ws + 64 * MB);
  ushort* w2kv = (ushort*)(ws + 67 * MB);
  ushort* att  = (ushort*)(ws + 72 * MB);
  ushort* wpj  = (ushort*)(ws + 88 * MB);
  ushort* kro  = (ushort*)(ws + 96 * MB);

  // one cast launch for everything (src=nullptr => zero-fill)
  CastTab t;
  const float* srcs[10] = {x, w_cq, w_ckv, w_krope, nullptr,
                           w_dqn, w_dqr, w_dkn, w_dv, w_proj};
  ushort* dsts[10] = {xbf, w1, w1 + 512 * 2048, w1 + 1024 * 2048, w1 + 1088 * 2048,
                      w2q, w2q + 2048 * 512, w2kv, w2kv + 2048 * 512, wpj};
  int ns[10] = {4096 * 2048, 512 * 2048, 512 * 2048, 64 * 2048, 64 * 2048,
                2048 * 512, 1024 * 512, 2048 * 512, 2048 * 512, 2048 * 2048};
  int blk = 0;
  for (int i = 0; i < 10; ++i) {
    t.seg[i].src = srcs[i];
    t.seg[i].dst = dsts[i];
    t.seg[i].n4 = ns[i] / 4;
    t.seg[i].blk0 = blk;
    blk += (ns[i] / 4 + 255) / 256;
  }
  cast_all_kernel<<<blk, 256, 0, stream>>>(t);

  // fused compress GEMM  [cq | ckv | krope]
  gemm_bt<false><<<dim3(32, 9), 256, 0, stream>>>(xbf, w1, g1, 1152, 2048);
  // RMSNorm + k_rope RoPE
  norm_rope1_kernel<<<4096, 256, 0, stream>>>(g1, w_qnorm, w_kvnorm, freqs, nq, nkv, kro);
  // Q + KV decompress, one launch
  gemm2_dual<<<dim3(32, 56), 256, 0, stream>>>(nq, w2q, g2q, nkv, w2kv, g2kv);
  // V transpose + Q RoPE, one launch
  misc_fused_kernel<<<2048 + 8192, 256, 0, stream>>>(g2q, freqs, g2kv, vT);
  // causal flash attention
  attn_kernel<<<512, 512, 0, stream>>>(g2q, g2kv, kro, vT, att);
  // output projection
  gemm_bt<false><<<dim3(32, 16), 256, 0, stream>>>(att, wpj, out, 2048, 2048);
}

// Round 6
// 489.470 us; speedup vs baseline: 1.1725x; 1.1725x over previous
//
#include <hip/hip_runtime.h>
#include <hip/hip_bf16.h>

// MLA forward, MI355X round 5 (resubmit; round-5 bench was infra timeout).
// attn = round-3 LDS-dbuf structure, LDS cut to 80KB (single-buf V + swizzled
// p_lds) => 2 blocks/CU; raw barriers with counted vmcnt (T4); XCD-aware block
// mapping; exp2/defer-max/setprio kept.
// B=2 S=2048 D=2048 H=16 NOPE=128 ROPE=64 VH=128 QR=KVR=512

typedef __attribute__((ext_vector_type(8))) short s8v;   // 8 bf16 (4 VGPR)
typedef __attribute__((ext_vector_type(4))) float f4v;   // 4 fp32 acc

#define DEV static __device__ __forceinline__

DEV ushort f2b(float f) {
  __hip_bfloat16 h = __float2bfloat16(f);
  return *reinterpret_cast<ushort*>(&h);
}
DEV float b2f(ushort u) {
  __hip_bfloat16 h = *reinterpret_cast<__hip_bfloat16*>(&u);
  return __bfloat162float(h);
}
DEV f4v mfma16(s8v a, s8v b, f4v c) {
  return __builtin_amdgcn_mfma_f32_16x16x32_bf16(a, b, c, 0, 0, 0);
}
DEV void gload16(const ushort* g, ushort* l) {
  __builtin_amdgcn_global_load_lds((const __attribute__((address_space(1))) void*)g,
                                   (__attribute__((address_space(3))) void*)l, 16, 0, 0);
}
DEV void barrier_raw() {
  __builtin_amdgcn_sched_barrier(0);
  __builtin_amdgcn_s_barrier();
  __builtin_amdgcn_sched_barrier(0);
}

// ---------------------------------------------------------------- all casts, one launch
struct CastSeg { const float* src; ushort* dst; int n4; int blk0; };
struct CastTab { CastSeg seg[10]; };

__global__ __launch_bounds__(256) void cast_all_kernel(CastTab t) {
  int b = blockIdx.x;
  int si = 0;
#pragma unroll
  for (int i = 1; i < 10; ++i) si = (b >= t.seg[i].blk0) ? i : si;
  int i4 = (b - t.seg[si].blk0) * 256 + threadIdx.x;
  if (i4 >= t.seg[si].n4) return;
  ushort4 o;
  if (t.seg[si].src) {
    float4 v = reinterpret_cast<const float4*>(t.seg[si].src)[i4];
    o.x = f2b(v.x); o.y = f2b(v.y); o.z = f2b(v.z); o.w = f2b(v.w);
  } else {
    o = ushort4{0, 0, 0, 0};
  }
  reinterpret_cast<ushort4*>(t.seg[si].dst)[i4] = o;
}

// ---------------------------------------------------------------- GEMM C = A * B^T
// 128x128 tile, BK=32, global_load_lds dwordx4, double-buffered, 4 waves.
template <bool BF16OUT>
DEV void gemm_core(const ushort* __restrict__ A, const ushort* __restrict__ B,
                   void* __restrict__ C, int N, int K, int row0, int col0,
                   ushort* a_lds0, ushort* a_lds1, ushort* b_lds0, ushort* b_lds1) {
  const int tid = threadIdx.x;
  const int lane = tid & 63, wv = tid >> 6;
  const int wm = wv >> 1, wn = wv & 1;
  const int l15 = lane & 15, l4 = lane >> 4;
  const int srow = lane >> 2;
  const int scol = (lane & 3) * 8;
  ushort* a_lds[2] = {a_lds0, a_lds1};
  ushort* b_lds[2] = {b_lds0, b_lds1};

  f4v acc[4][4];
#pragma unroll
  for (int i = 0; i < 4; ++i)
#pragma unroll
    for (int j = 0; j < 4; ++j) acc[i][j] = f4v{0.f, 0.f, 0.f, 0.f};

  auto stage = [&](int k0, int bsel) {
#pragma unroll
    for (int i = 0; i < 2; ++i) {
      int s = wv * 2 + i;
      gload16(&A[(size_t)(row0 + s * 16 + srow) * K + k0 + scol], &a_lds[bsel][s * 512]);
      gload16(&B[(size_t)(col0 + s * 16 + srow) * K + k0 + scol], &b_lds[bsel][s * 512]);
    }
  };

  stage(0, 0);
  int cur = 0;
  for (int k0 = 0; k0 < K; k0 += 32) {
    __syncthreads();
    if (k0 + 32 < K) stage(k0 + 32, cur ^ 1);
    s8v af[4], bfr[4];
#pragma unroll
    for (int mi = 0; mi < 4; ++mi)
      af[mi] = *reinterpret_cast<const s8v*>(&a_lds[cur][(wm * 64 + mi * 16 + l15) * 32 + 8 * l4]);
#pragma unroll
    for (int ni = 0; ni < 4; ++ni)
      bfr[ni] = *reinterpret_cast<const s8v*>(&b_lds[cur][(wn * 64 + ni * 16 + l15) * 32 + 8 * l4]);
#pragma unroll
    for (int mi = 0; mi < 4; ++mi)
#pragma unroll
      for (int ni = 0; ni < 4; ++ni) acc[mi][ni] = mfma16(af[mi], bfr[ni], acc[mi][ni]);
    cur ^= 1;
  }

#pragma unroll
  for (int mi = 0; mi < 4; ++mi)
#pragma unroll
    for (int ni = 0; ni < 4; ++ni)
#pragma unroll
      for (int j = 0; j < 4; ++j) {
        int r = row0 + wm * 64 + mi * 16 + l4 * 4 + j;   // C/D: row=(lane>>4)*4+reg
        int cl = col0 + wn * 64 + ni * 16 + l15;          //      col=lane&15
        if (BF16OUT)
          reinterpret_cast<ushort*>(C)[(size_t)r * N + cl] = f2b(acc[mi][ni][j]);
        else
          reinterpret_cast<float*>(C)[(size_t)r * N + cl] = acc[mi][ni][j];
      }
}

template <bool BF16OUT>
__global__ __launch_bounds__(256) void gemm_bt(const ushort* __restrict__ A,
                                               const ushort* __restrict__ B,
                                               void* __restrict__ C, int N, int K) {
  __shared__ ushort a0[128 * 32], a1[128 * 32], b0[128 * 32], b1[128 * 32];
  gemm_core<BF16OUT>(A, B, C, N, K, blockIdx.x * 128, blockIdx.y * 128, a0, a1, b0, b1);
}

// Q-decompress (N=3072) and KV-decompress (N=4096) in one launch. K=512, M=4096.
__global__ __launch_bounds__(256) void gemm2_dual(const ushort* __restrict__ nq,
                                                  const ushort* __restrict__ w2q,
                                                  ushort* __restrict__ g2q,
                                                  const ushort* __restrict__ nkv,
                                                  const ushort* __restrict__ w2kv,
                                                  ushort* __restrict__ g2kv) {
  __shared__ ushort a0[128 * 32], a1[128 * 32], b0[128 * 32], b1[128 * 32];
  int by = blockIdx.y;
  if (by < 24)
    gemm_core<true>(nq, w2q, g2q, 3072, 512, blockIdx.x * 128, by * 128, a0, a1, b0, b1);
  else
    gemm_core<true>(nkv, w2kv, g2kv, 4096, 512, blockIdx.x * 128, (by - 24) * 128, a0, a1, b0, b1);
}

// ---------------------------------------------------------------- RMSNorm(cq,ckv) + RoPE(k_rope)
__global__ __launch_bounds__(256) void norm_rope1_kernel(
    const float* __restrict__ g1, const float* __restrict__ wq, const float* __restrict__ wkv,
    const float* __restrict__ freqs, ushort* __restrict__ nq, ushort* __restrict__ nkv,
    ushort* __restrict__ kro) {
  const int m = blockIdx.x;       // 0..4095 = b*2048+s
  const int s = m & 2047;
  const int tid = threadIdx.x;
  __shared__ float red[4];
  const float* row = g1 + (size_t)m * 1152;

  float v0 = row[tid], v1 = row[tid + 256];
  float ss = v0 * v0 + v1 * v1;
#pragma unroll
  for (int off = 32; off > 0; off >>= 1) ss += __shfl_down(ss, off);
  if ((tid & 63) == 0) red[tid >> 6] = ss;
  __syncthreads();
  float r = rsqrtf((red[0] + red[1] + red[2] + red[3]) * (1.0f / 512.0f) + 1e-6f);
  nq[(size_t)m * 512 + tid] = f2b(v0 * r * wq[tid]);
  nq[(size_t)m * 512 + tid + 256] = f2b(v1 * r * wq[tid + 256]);

  float u0 = row[512 + tid], u1 = row[512 + tid + 256];
  float ss2 = u0 * u0 + u1 * u1;
#pragma unroll
  for (int off = 32; off > 0; off >>= 1) ss2 += __shfl_down(ss2, off);
  __syncthreads();
  if ((tid & 63) == 0) red[tid >> 6] = ss2;
  __syncthreads();
  float r2 = rsqrtf((red[0] + red[1] + red[2] + red[3]) * (1.0f / 512.0f) + 1e-6f);
  nkv[(size_t)m * 512 + tid] = f2b(u0 * r2 * wkv[tid]);
  nkv[(size_t)m * 512 + tid + 256] = f2b(u1 * r2 * wkv[tid + 256]);

  if (tid < 32) {
    float x0 = row[1024 + 2 * tid], x1 = row[1024 + 2 * tid + 1];
    float c = freqs[s * 64 + 2 * tid], sn = freqs[s * 64 + 2 * tid + 1];
    kro[(size_t)m * 64 + 2 * tid] = f2b((x0 * c - x1 * sn) * (1.0f / 16.0f));
    kro[(size_t)m * 64 + 2 * tid + 1] = f2b((x0 * sn + x1 * c) * (1.0f / 16.0f));
  }
}

// ---------------------------------------------------------------- V transpose + Q RoPE, one launch
__global__ __launch_bounds__(256) void misc_fused_kernel(ushort* __restrict__ g2q,
                                                         const float* __restrict__ freqs,
                                                         const ushort* __restrict__ g2kv,
                                                         ushort* __restrict__ vT) {
  const int tid = threadIdx.x;
  if (blockIdx.x < 2048) {   // ---- V transpose: g2kv v-section -> vT (B,H,128,S)
    int blk = blockIdx.x;
    int bh = blk >> 6;
    int rem = blk & 63;
    int st = rem >> 1, dt = rem & 1;
    int b = bh >> 4, h = bh & 15;
    __shared__ ushort t[64][72];
#pragma unroll
    for (int it = 0; it < 2; ++it) {
      int c = tid + it * 256;
      int sl = c >> 3, cc = (c & 7) * 8;
      *reinterpret_cast<uint4*>(&t[sl][cc]) = *reinterpret_cast<const uint4*>(
          &g2kv[(size_t)(b * 2048 + st * 64 + sl) * 4096 + 2048 + h * 128 + dt * 64 + cc]);
    }
    __syncthreads();
#pragma unroll
    for (int it = 0; it < 2; ++it) {
      int c = tid + it * 256;
      int dl = c >> 3, cc = (c & 7) * 8;
      ushort tmp[8];
#pragma unroll
      for (int e = 0; e < 8; ++e) tmp[e] = t[cc + e][dl];
      *reinterpret_cast<uint4*>(&vT[(size_t)(bh * 128 + dt * 64 + dl) * 2048 + st * 64 + cc]) =
          *reinterpret_cast<uint4*>(tmp);
    }
  } else {                    // ---- RoPE on q_rope (in-place)
    int idx = (blockIdx.x - 2048) * 256 + tid;  // 4096*16*32
    int m = idx >> 9;
    int rem = idx & 511;
    int h = rem >> 5, j = rem & 31;
    int s = m & 2047;
    size_t base = (size_t)m * 3072 + 2048 + h * 64 + 2 * j;
    ushort2 pr = *reinterpret_cast<ushort2*>(&g2q[base]);
    float x0 = b2f(pr.x), x1 = b2f(pr.y);
    float c = freqs[s * 64 + 2 * j], sn = freqs[s * 64 + 2 * j + 1];
    ushort2 o;
    o.x = f2b(x0 * c - x1 * sn);
    o.y = f2b(x0 * sn + x1 * c);
    *reinterpret_cast<ushort2*>(&g2q[base]) = o;
  }
}

// ---------------------------------------------------------------- causal flash attention
// QBLK=128, 8 waves x 16 q-rows, KVBLK=64. K: LDS dbuf (gload_lds, XOR swizzle).
// V: LDS single-buf, staged each iter, covered by counted vmcnt (T4) + raw barriers.
// LDS exactly 80KB -> 2 blocks/CU. XCD mapping: 4 heads per XCD (K/V L2-resident).
__global__ __launch_bounds__(512, 4) void attn_kernel(const ushort* __restrict__ q,     // 4096x3072
                                                      const ushort* __restrict__ knope, // 4096x4096
                                                      const ushort* __restrict__ kro,   // 4096x64
                                                      const ushort* __restrict__ vT,    // (B*H*128)x2048
                                                      ushort* __restrict__ out) {       // 4096x2048
  const int p = blockIdx.x;                 // 512 blocks
  const int bh = 4 * (p & 7) + ((p >> 3) & 3);   // xcd = p%8 owns 4 heads
  const int qt = 15 - (p >> 5);             // heavy-first (LPT)
  const int b = bh >> 4, h = bh & 15;
  const int tid = threadIdx.x, lane = tid & 63, w = tid >> 6;
  const int l15 = lane & 15, l4 = lane >> 4;

  __shared__ ushort kbuf[2][64 * 192];      // 48KB dbuf, linear, XOR-swizzled
  __shared__ ushort vbuf[128 * 64];         // 16KB single-buf, XOR-swizzled
  __shared__ ushort p_lds[8][1024];         // 16KB per-wave P 16x64, XOR-swizzled

  s8v qf[6];
  {
    const size_t qbase = (size_t)(b * 2048 + qt * 128 + w * 16 + l15) * 3072;
#pragma unroll
    for (int kc = 0; kc < 4; ++kc)
      qf[kc] = *reinterpret_cast<const s8v*>(&q[qbase + h * 128 + kc * 32 + 8 * l4]);
#pragma unroll
    for (int kc = 4; kc < 6; ++kc)
      qf[kc] = *reinterpret_cast<const s8v*>(&q[qbase + 2048 + h * 64 + (kc - 4) * 32 + 8 * l4]);
  }

  f4v oacc[8];
#pragma unroll
  for (int i = 0; i < 8; ++i) oacc[i] = f4v{0.f, 0.f, 0.f, 0.f};
  float m_r[4] = {-INFINITY, -INFINITY, -INFINITY, -INFINITY};
  float l_r[4] = {0.f, 0.f, 0.f, 0.f};
  const float sc2 = 0.07216878364870323f * 1.44269504f;  // 1/sqrt(192) * log2(e)
  const int nkt = 2 * qt + 2;
  const int kbase = b * 2048;

  // K tile: logical [row<64][col<192], byte o=row*384+col*2, phys = o ^ ((row&7)<<4).
  auto stageK = [&](int kt, int bsel) {
    const int krow0 = kbase + kt * 64;
#pragma unroll
    for (int i = 0; i < 3; ++i) {           // 24 segs of 1KB, 3 per wave
      int s = w * 3 + i;
      int pp = s * 1024 + lane * 16;
      int row = pp / 384;
      int col = ((pp ^ ((row & 7) << 4)) - row * 384) >> 1;
      const ushort* src = (col < 128)
          ? &knope[(size_t)(krow0 + row) * 4096 + h * 128 + col]
          : &kro[(size_t)(krow0 + row) * 64 + (col - 128)];
      gload16(src, &kbuf[bsel][s * 512]);
    }
  };
  // V tile: logical [d<128][key<64], byte o=d*128+key*2, phys = o ^ ((d&7)<<4).
  auto stageV = [&](int kt) {
#pragma unroll
    for (int i = 0; i < 2; ++i) {           // 16 segs of 1KB, 2 per wave
      int s = w * 2 + i;
      int pp = s * 1024 + lane * 16;
      int d = pp >> 7;
      int key = ((pp ^ ((d & 7) << 4)) & 127) >> 1;
      gload16(&vT[(size_t)(bh * 128 + d) * 2048 + kt * 64 + key], &vbuf[s * 512]);
    }
  };

  stageK(0, 0);
  int cur = 0;
  for (int kt = 0; kt < nkt; ++kt) {
    // top barrier: K[kt] landed (issuer vmcnt drained), prev PV reads of vbuf done
    asm volatile("s_waitcnt vmcnt(0)" ::: "memory");
    barrier_raw();
    stageV(kt);                              // 2 loads/wave -> vbuf (issued FIRST)
    if (kt + 1 < nkt) stageK(kt + 1, cur ^ 1);  // 3 loads/wave, stay in flight past mid barrier
    const char* kb = (const char*)kbuf[cur];

    // S = Q K^T (16 q x 64 keys per wave)
    f4v sacc[4];
    __builtin_amdgcn_s_setprio(1);
#pragma unroll
    for (int nb = 0; nb < 4; ++nb) {
      sacc[nb] = f4v{0.f, 0.f, 0.f, 0.f};
      const int row = nb * 16 + l15;
      const int sw = (row & 7) << 4;
#pragma unroll
      for (int kc = 0; kc < 6; ++kc) {
        s8v bfr = *reinterpret_cast<const s8v*>(kb + row * 384 + ((kc * 64 + l4 * 16) ^ sw));
        sacc[nb] = mfma16(qf[kc], bfr, sacc[nb]);
      }
    }
    __builtin_amdgcn_s_setprio(0);

    // scale (exp2 space) + causal mask
    const int qrow0 = qt * 128 + w * 16 + l4 * 4;
#pragma unroll
    for (int nb = 0; nb < 4; ++nb) {
      int key = kt * 64 + nb * 16 + l15;
#pragma unroll
      for (int j = 0; j < 4; ++j) {
        float sv = sacc[nb][j] * sc2;
        if (kt >= 2 * qt && key > qrow0 + j) sv = -INFINITY;
        sacc[nb][j] = sv;
      }
    }
    // row max over 64 keys
    float mx[4];
#pragma unroll
    for (int j = 0; j < 4; ++j)
      mx[j] = fmaxf(fmaxf(sacc[0][j], sacc[1][j]), fmaxf(sacc[2][j], sacc[3][j]));
#pragma unroll
    for (int off = 1; off < 16; off <<= 1)
#pragma unroll
      for (int j = 0; j < 4; ++j) mx[j] = fmaxf(mx[j], __shfl_xor(mx[j], off));

    // T13 defer-max
    float need = fmaxf(fmaxf(mx[0] - m_r[0], mx[1] - m_r[1]),
                       fmaxf(mx[2] - m_r[2], mx[3] - m_r[3]));
    if (!__all(need <= 8.0f)) {
      float al[4];
#pragma unroll
      for (int j = 0; j < 4; ++j) {
        float mnew = fmaxf(m_r[j], mx[j]);
        al[j] = exp2f(m_r[j] - mnew);
        m_r[j] = mnew;
        l_r[j] *= al[j];
      }
#pragma unroll
      for (int nv = 0; nv < 8; ++nv)
#pragma unroll
        for (int j = 0; j < 4; ++j) oacc[nv][j] *= al[j];
    }
    // P = exp2(s' - m'), row-sums
    float rs[4] = {0.f, 0.f, 0.f, 0.f};
#pragma unroll
    for (int nb = 0; nb < 4; ++nb)
#pragma unroll
      for (int j = 0; j < 4; ++j) {
        float pv = exp2f(sacc[nb][j] - m_r[j]);
        sacc[nb][j] = pv;
        rs[j] += pv;
      }
#pragma unroll
    for (int off = 1; off < 16; off <<= 1)
#pragma unroll
      for (int j = 0; j < 4; ++j) rs[j] += __shfl_xor(rs[j], off);
#pragma unroll
    for (int j = 0; j < 4; ++j) l_r[j] += rs[j];
    // P -> p_lds (swizzled: col c stored at c ^ ((row&7)<<3))
#pragma unroll
    for (int nb = 0; nb < 4; ++nb)
#pragma unroll
      for (int j = 0; j < 4; ++j) {
        int r = l4 * 4 + j;
        p_lds[w][r * 64 + ((nb * 16 + l15) ^ ((r & 7) << 3))] = f2b(sacc[nb][j]);
      }

    // mid barrier: V[kt] done (counted: K[kt+1]'s 3 loads stay outstanding)
    if (kt + 1 < nkt) {
      asm volatile("s_waitcnt vmcnt(3)" ::: "memory");
    } else {
      asm volatile("s_waitcnt vmcnt(0)" ::: "memory");
    }
    barrier_raw();

    // O += P V
    const char* vb = (const char*)vbuf;
    __builtin_amdgcn_s_setprio(1);
#pragma unroll
    for (int kc2 = 0; kc2 < 2; ++kc2) {
      s8v pf = *reinterpret_cast<const s8v*>(
          &p_lds[w][l15 * 64 + ((kc2 * 32 + 8 * l4) ^ ((l15 & 7) << 3))]);
#pragma unroll
      for (int nv = 0; nv < 8; ++nv) {
        const int d = nv * 16 + l15;
        s8v vf = *reinterpret_cast<const s8v*>(vb + d * 128 + ((kc2 * 64 + l4 * 16) ^ ((d & 7) << 4)));
        oacc[nv] = mfma16(pf, vf, oacc[nv]);
      }
    }
    __builtin_amdgcn_s_setprio(0);
    cur ^= 1;
  }

  // epilogue: normalize + store (B,S,H*128) bf16
#pragma unroll
  for (int j = 0; j < 4; ++j) {
    float inv = 1.0f / l_r[j];
    int m = b * 2048 + qt * 128 + w * 16 + l4 * 4 + j;
#pragma unroll
    for (int nv = 0; nv < 8; ++nv)
      out[(size_t)m * 2048 + h * 128 + nv * 16 + l15] = f2b(oacc[nv][j] * inv);
  }
}

// ---------------------------------------------------------------- launch
// Workspace layout (lifetime-aliased, peak 96.5 MiB):
//   [ 0,32M)  g2kv   overlay: g1 fp32 18M
//   [32,56M)  g2q    overlay: xbf 16M @32M, w1 4.5M @48M
//   [56,72M)  vT     overlay: nq 4M @56M, nkv 4M @60M, w2q 3M @64M, w2kv 4M @67M
//   [72,88M)  att
//   [88,96M)  wpj
//   [96,96.5M) kro
extern "C" void kernel_launch(void* const* d_in, const int* in_sizes, int n_in,
                              void* d_out, int out_size, void* d_ws, size_t ws_size,
                              hipStream_t stream) {
  const float* x       = (const float*)d_in[0];
  const float* freqs   = (const float*)d_in[2];
  const float* w_cq    = (const float*)d_in[3];
  const float* w_qnorm = (const float*)d_in[4];
  const float* w_dqn   = (const float*)d_in[5];
  const float* w_dqr   = (const float*)d_in[6];
  const float* w_ckv   = (const float*)d_in[7];
  const float* w_kvnorm= (const float*)d_in[8];
  const float* w_dkn   = (const float*)d_in[9];
  const float* w_dv    = (const float*)d_in[10];
  const float* w_krope = (const float*)d_in[11];
  const float* w_proj  = (const float*)d_in[12];
  float* out = (float*)d_out;

  char* ws = (char*)d_ws;
  const size_t MB = 1ull << 20;
  ushort* g2kv = (ushort*)(ws + 0);
  float*  g1   = (float*) (ws + 0);
  ushort* g2q  = (ushort*)(ws + 32 * MB);
  ushort* xbf  = (ushort*)(ws + 32 * MB);
  ushort* w1   = (ushort*)(ws + 48 * MB);
  ushort* vT   = (ushort*)(ws + 56 * MB);
  ushort* nq   = (ushort*)(ws + 56 * MB);
  ushort* nkv  = (ushort*)(ws + 60 * MB);
  ushort* w2q  = (ushort*)(ws + 64 * MB);
  ushort* w2kv = (ushort*)(ws + 67 * MB);
  ushort* att  = (ushort*)(ws + 72 * MB);
  ushort* wpj  = (ushort*)(ws + 88 * MB);
  ushort* kro  = (ushort*)(ws + 96 * MB);

  // one cast launch for everything (src=nullptr => zero-fill)
  CastTab t;
  const float* srcs[10] = {x, w_cq, w_ckv, w_krope, nullptr,
                           w_dqn, w_dqr, w_dkn, w_dv, w_proj};
  ushort* dsts[10] = {xbf, w1, w1 + 512 * 2048, w1 + 1024 * 2048, w1 + 1088 * 2048,
                      w2q, w2q + 2048 * 512, w2kv, w2kv + 2048 * 512, wpj};
  int ns[10] = {4096 * 2048, 512 * 2048, 512 * 2048, 64 * 2048, 64 * 2048,
                2048 * 512, 1024 * 512, 2048 * 512, 2048 * 512, 2048 * 2048};
  int blk = 0;
  for (int i = 0; i < 10; ++i) {
    t.seg[i].src = srcs[i];
    t.seg[i].dst = dsts[i];
    t.seg[i].n4 = ns[i] / 4;
    t.seg[i].blk0 = blk;
    blk += (ns[i] / 4 + 255) / 256;
  }
  cast_all_kernel<<<blk, 256, 0, stream>>>(t);

  // fused compress GEMM  [cq | ckv | krope]
  gemm_bt<false><<<dim3(32, 9), 256, 0, stream>>>(xbf, w1, g1, 1152, 2048);
  // RMSNorm + k_rope RoPE
  norm_rope1_kernel<<<4096, 256, 0, stream>>>(g1, w_qnorm, w_kvnorm, freqs, nq, nkv, kro);
  // Q + KV decompress, one launch
  gemm2_dual<<<dim3(32, 56), 256, 0, stream>>>(nq, w2q, g2q, nkv, w2kv, g2kv);
  // V transpose + Q RoPE, one launch
  misc_fused_kernel<<<2048 + 8192, 256, 0, stream>>>(g2q, freqs, g2kv, vT);
  // causal flash attention
  attn_kernel<<<512, 512, 0, stream>>>(g2q, g2kv, kro, vT, att);
  // output projection
  gemm_bt<false><<<dim3(32, 16), 256, 0, stream>>>(att, wpj, out, 2048, 2048);
}

// Round 7
// 461.800 us; speedup vs baseline: 1.2427x; 1.0599x over previous
//
#include <hip/hip_runtime.h>
#include <hip/hip_bf16.h>

// MLA forward, MI355X round 7: attn with swapped QK^T (P lane-local, no p_lds),
// 64KB LDS => 2 blocks/CU certain, balanced heavy+light block pairing,
// counted-vmcnt single-buf V, dbuf K. Non-attn pipeline unchanged.
// B=2 S=2048 D=2048 H=16 NOPE=128 ROPE=64 VH=128 QR=KVR=512

typedef __attribute__((ext_vector_type(8))) short s8v;   // 8 bf16 (4 VGPR)
typedef __attribute__((ext_vector_type(4))) float f4v;   // 4 fp32 acc

#define DEV static __device__ __forceinline__

DEV ushort f2b(float f) {
  __hip_bfloat16 h = __float2bfloat16(f);
  return *reinterpret_cast<ushort*>(&h);
}
DEV float b2f(ushort u) {
  __hip_bfloat16 h = *reinterpret_cast<__hip_bfloat16*>(&u);
  return __bfloat162float(h);
}
DEV f4v mfma16(s8v a, s8v b, f4v c) {
  return __builtin_amdgcn_mfma_f32_16x16x32_bf16(a, b, c, 0, 0, 0);
}
DEV void gload16(const ushort* g, ushort* l) {
  __builtin_amdgcn_global_load_lds((const __attribute__((address_space(1))) void*)g,
                                   (__attribute__((address_space(3))) void*)l, 16, 0, 0);
}
DEV void barrier_raw() {
  __builtin_amdgcn_sched_barrier(0);
  __builtin_amdgcn_s_barrier();
  __builtin_amdgcn_sched_barrier(0);
}

// ---------------------------------------------------------------- all casts, one launch
struct CastSeg { const float* src; ushort* dst; int n4; int blk0; };
struct CastTab { CastSeg seg[10]; };

__global__ __launch_bounds__(256) void cast_all_kernel(CastTab t) {
  int b = blockIdx.x;
  int si = 0;
#pragma unroll
  for (int i = 1; i < 10; ++i) si = (b >= t.seg[i].blk0) ? i : si;
  int i4 = (b - t.seg[si].blk0) * 256 + threadIdx.x;
  if (i4 >= t.seg[si].n4) return;
  ushort4 o;
  if (t.seg[si].src) {
    float4 v = reinterpret_cast<const float4*>(t.seg[si].src)[i4];
    o.x = f2b(v.x); o.y = f2b(v.y); o.z = f2b(v.z); o.w = f2b(v.w);
  } else {
    o = ushort4{0, 0, 0, 0};
  }
  reinterpret_cast<ushort4*>(t.seg[si].dst)[i4] = o;
}

// ---------------------------------------------------------------- GEMM C = A * B^T
// 128x128 tile, BK=32, global_load_lds dwordx4, double-buffered, 4 waves.
template <bool BF16OUT>
DEV void gemm_core(const ushort* __restrict__ A, const ushort* __restrict__ B,
                   void* __restrict__ C, int N, int K, int row0, int col0,
                   ushort* a_lds0, ushort* a_lds1, ushort* b_lds0, ushort* b_lds1) {
  const int tid = threadIdx.x;
  const int lane = tid & 63, wv = tid >> 6;
  const int wm = wv >> 1, wn = wv & 1;
  const int l15 = lane & 15, l4 = lane >> 4;
  const int srow = lane >> 2;
  const int scol = (lane & 3) * 8;
  ushort* a_lds[2] = {a_lds0, a_lds1};
  ushort* b_lds[2] = {b_lds0, b_lds1};

  f4v acc[4][4];
#pragma unroll
  for (int i = 0; i < 4; ++i)
#pragma unroll
    for (int j = 0; j < 4; ++j) acc[i][j] = f4v{0.f, 0.f, 0.f, 0.f};

  auto stage = [&](int k0, int bsel) {
#pragma unroll
    for (int i = 0; i < 2; ++i) {
      int s = wv * 2 + i;
      gload16(&A[(size_t)(row0 + s * 16 + srow) * K + k0 + scol], &a_lds[bsel][s * 512]);
      gload16(&B[(size_t)(col0 + s * 16 + srow) * K + k0 + scol], &b_lds[bsel][s * 512]);
    }
  };

  stage(0, 0);
  int cur = 0;
  for (int k0 = 0; k0 < K; k0 += 32) {
    __syncthreads();
    if (k0 + 32 < K) stage(k0 + 32, cur ^ 1);
    s8v af[4], bfr[4];
#pragma unroll
    for (int mi = 0; mi < 4; ++mi)
      af[mi] = *reinterpret_cast<const s8v*>(&a_lds[cur][(wm * 64 + mi * 16 + l15) * 32 + 8 * l4]);
#pragma unroll
    for (int ni = 0; ni < 4; ++ni)
      bfr[ni] = *reinterpret_cast<const s8v*>(&b_lds[cur][(wn * 64 + ni * 16 + l15) * 32 + 8 * l4]);
#pragma unroll
    for (int mi = 0; mi < 4; ++mi)
#pragma unroll
      for (int ni = 0; ni < 4; ++ni) acc[mi][ni] = mfma16(af[mi], bfr[ni], acc[mi][ni]);
    cur ^= 1;
  }

#pragma unroll
  for (int mi = 0; mi < 4; ++mi)
#pragma unroll
    for (int ni = 0; ni < 4; ++ni)
#pragma unroll
      for (int j = 0; j < 4; ++j) {
        int r = row0 + wm * 64 + mi * 16 + l4 * 4 + j;   // C/D: row=(lane>>4)*4+reg
        int cl = col0 + wn * 64 + ni * 16 + l15;          //      col=lane&15
        if (BF16OUT)
          reinterpret_cast<ushort*>(C)[(size_t)r * N + cl] = f2b(acc[mi][ni][j]);
        else
          reinterpret_cast<float*>(C)[(size_t)r * N + cl] = acc[mi][ni][j];
      }
}

template <bool BF16OUT>
__global__ __launch_bounds__(256) void gemm_bt(const ushort* __restrict__ A,
                                               const ushort* __restrict__ B,
                                               void* __restrict__ C, int N, int K) {
  __shared__ ushort a0[128 * 32], a1[128 * 32], b0[128 * 32], b1[128 * 32];
  gemm_core<BF16OUT>(A, B, C, N, K, blockIdx.x * 128, blockIdx.y * 128, a0, a1, b0, b1);
}

// Q-decompress (N=3072) and KV-decompress (N=4096) in one launch. K=512, M=4096.
__global__ __launch_bounds__(256) void gemm2_dual(const ushort* __restrict__ nq,
                                                  const ushort* __restrict__ w2q,
                                                  ushort* __restrict__ g2q,
                                                  const ushort* __restrict__ nkv,
                                                  const ushort* __restrict__ w2kv,
                                                  ushort* __restrict__ g2kv) {
  __shared__ ushort a0[128 * 32], a1[128 * 32], b0[128 * 32], b1[128 * 32];
  int by = blockIdx.y;
  if (by < 24)
    gemm_core<true>(nq, w2q, g2q, 3072, 512, blockIdx.x * 128, by * 128, a0, a1, b0, b1);
  else
    gemm_core<true>(nkv, w2kv, g2kv, 4096, 512, blockIdx.x * 128, (by - 24) * 128, a0, a1, b0, b1);
}

// ---------------------------------------------------------------- RMSNorm(cq,ckv) + RoPE(k_rope)
__global__ __launch_bounds__(256) void norm_rope1_kernel(
    const float* __restrict__ g1, const float* __restrict__ wq, const float* __restrict__ wkv,
    const float* __restrict__ freqs, ushort* __restrict__ nq, ushort* __restrict__ nkv,
    ushort* __restrict__ kro) {
  const int m = blockIdx.x;       // 0..4095 = b*2048+s
  const int s = m & 2047;
  const int tid = threadIdx.x;
  __shared__ float red[4];
  const float* row = g1 + (size_t)m * 1152;

  float v0 = row[tid], v1 = row[tid + 256];
  float ss = v0 * v0 + v1 * v1;
#pragma unroll
  for (int off = 32; off > 0; off >>= 1) ss += __shfl_down(ss, off);
  if ((tid & 63) == 0) red[tid >> 6] = ss;
  __syncthreads();
  float r = rsqrtf((red[0] + red[1] + red[2] + red[3]) * (1.0f / 512.0f) + 1e-6f);
  nq[(size_t)m * 512 + tid] = f2b(v0 * r * wq[tid]);
  nq[(size_t)m * 512 + tid + 256] = f2b(v1 * r * wq[tid + 256]);

  float u0 = row[512 + tid], u1 = row[512 + tid + 256];
  float ss2 = u0 * u0 + u1 * u1;
#pragma unroll
  for (int off = 32; off > 0; off >>= 1) ss2 += __shfl_down(ss2, off);
  __syncthreads();
  if ((tid & 63) == 0) red[tid >> 6] = ss2;
  __syncthreads();
  float r2 = rsqrtf((red[0] + red[1] + red[2] + red[3]) * (1.0f / 512.0f) + 1e-6f);
  nkv[(size_t)m * 512 + tid] = f2b(u0 * r2 * wkv[tid]);
  nkv[(size_t)m * 512 + tid + 256] = f2b(u1 * r2 * wkv[tid + 256]);

  if (tid < 32) {
    float x0 = row[1024 + 2 * tid], x1 = row[1024 + 2 * tid + 1];
    float c = freqs[s * 64 + 2 * tid], sn = freqs[s * 64 + 2 * tid + 1];
    kro[(size_t)m * 64 + 2 * tid] = f2b((x0 * c - x1 * sn) * (1.0f / 16.0f));
    kro[(size_t)m * 64 + 2 * tid + 1] = f2b((x0 * sn + x1 * c) * (1.0f / 16.0f));
  }
}

// ---------------------------------------------------------------- V transpose + Q RoPE, one launch
__global__ __launch_bounds__(256) void misc_fused_kernel(ushort* __restrict__ g2q,
                                                         const float* __restrict__ freqs,
                                                         const ushort* __restrict__ g2kv,
                                                         ushort* __restrict__ vT) {
  const int tid = threadIdx.x;
  if (blockIdx.x < 2048) {   // ---- V transpose: g2kv v-section -> vT (B,H,128,S)
    int blk = blockIdx.x;
    int bh = blk >> 6;
    int rem = blk & 63;
    int st = rem >> 1, dt = rem & 1;
    int b = bh >> 4, h = bh & 15;
    __shared__ ushort t[64][72];
#pragma unroll
    for (int it = 0; it < 2; ++it) {
      int c = tid + it * 256;
      int sl = c >> 3, cc = (c & 7) * 8;
      *reinterpret_cast<uint4*>(&t[sl][cc]) = *reinterpret_cast<const uint4*>(
          &g2kv[(size_t)(b * 2048 + st * 64 + sl) * 4096 + 2048 + h * 128 + dt * 64 + cc]);
    }
    __syncthreads();
#pragma unroll
    for (int it = 0; it < 2; ++it) {
      int c = tid + it * 256;
      int dl = c >> 3, cc = (c & 7) * 8;
      ushort tmp[8];
#pragma unroll
      for (int e = 0; e < 8; ++e) tmp[e] = t[cc + e][dl];
      *reinterpret_cast<uint4*>(&vT[(size_t)(bh * 128 + dt * 64 + dl) * 2048 + st * 64 + cc]) =
          *reinterpret_cast<uint4*>(tmp);
    }
  } else {                    // ---- RoPE on q_rope (in-place)
    int idx = (blockIdx.x - 2048) * 256 + tid;  // 4096*16*32
    int m = idx >> 9;
    int rem = idx & 511;
    int h = rem >> 5, j = rem & 31;
    int s = m & 2047;
    size_t base = (size_t)m * 3072 + 2048 + h * 64 + 2 * j;
    ushort2 pr = *reinterpret_cast<ushort2*>(&g2q[base]);
    float x0 = b2f(pr.x), x1 = b2f(pr.y);
    float c = freqs[s * 64 + 2 * j], sn = freqs[s * 64 + 2 * j + 1];
    ushort2 o;
    o.x = f2b(x0 * c - x1 * sn);
    o.y = f2b(x0 * sn + x1 * c);
    *reinterpret_cast<ushort2*>(&g2q[base]) = o;
  }
}

// ---------------------------------------------------------------- causal flash attention
// QBLK=128, 8 waves x 16 q-rows, KVBLK=64. Swapped QK^T: sacc[nb][j] =
// P[q=l15][key=nb*16+4*l4+j] -> softmax per-lane scalar, P->A-frag via shfl
// (no p_lds). K dbuf 48K + V single 16K = 64KB LDS -> 2 blocks/CU certain.
// Balanced pairing: co-resident blocks (p, p+256) have qt sums == 36.
__global__ __launch_bounds__(512, 4) void attn_kernel(const ushort* __restrict__ q,     // 4096x3072
                                                      const ushort* __restrict__ knope, // 4096x4096
                                                      const ushort* __restrict__ kro,   // 4096x64
                                                      const ushort* __restrict__ vT,    // (B*H*128)x2048
                                                      ushort* __restrict__ out) {       // 4096x2048
  const int p = blockIdx.x;                 // 512 blocks
  const int a = (p >> 5) & 7;
  const int qt = (p < 256) ? (15 - a) : a;  // balanced heavy/light pairing
  const int bh = p & 31;                    // XCD p%8 sees 4 distinct bh (L2-resident K/V)
  const int b = bh >> 4, h = bh & 15;
  const int tid = threadIdx.x, lane = tid & 63, w = tid >> 6;
  const int l15 = lane & 15, l4 = lane >> 4;

  __shared__ ushort kbuf[2][64 * 192];      // 48KB dbuf, linear, XOR-swizzled
  __shared__ ushort vbuf[128 * 64];         // 16KB single-buf, XOR-swizzled

  // Q fragments (B-operand of swapped QK^T): col=q=l15, k at 8*l4
  s8v qf[6];
  {
    const size_t qbase = (size_t)(b * 2048 + qt * 128 + w * 16 + l15) * 3072;
#pragma unroll
    for (int kc = 0; kc < 4; ++kc)
      qf[kc] = *reinterpret_cast<const s8v*>(&q[qbase + h * 128 + kc * 32 + 8 * l4]);
#pragma unroll
    for (int kc = 4; kc < 6; ++kc)
      qf[kc] = *reinterpret_cast<const s8v*>(&q[qbase + 2048 + h * 64 + (kc - 4) * 32 + 8 * l4]);
  }

  f4v oacc[8];                              // oacc[nv][j] = O[q=w*16+4*l4+j][d=nv*16+l15]
#pragma unroll
  for (int i = 0; i < 8; ++i) oacc[i] = f4v{0.f, 0.f, 0.f, 0.f};
  float m_r = -INFINITY, l_r = 0.f;         // softmax state for q = w*16 + l15
  const float sc2 = 0.07216878364870323f * 1.44269504f;  // 1/sqrt(192)*log2(e)
  const int nkt = 2 * qt + 2;
  const int kbase = b * 2048;
  const int myq = qt * 128 + w * 16 + l15;  // this lane's q row (softmax space)

  auto stageK = [&](int kt, int bsel) {
    const int krow0 = kbase + kt * 64;
#pragma unroll
    for (int i = 0; i < 3; ++i) {           // 24 segs of 1KB, 3 per wave
      int s = w * 3 + i;
      int pp = s * 1024 + lane * 16;
      int row = pp / 384;
      int col = ((pp ^ ((row & 7) << 4)) - row * 384) >> 1;
      const ushort* src = (col < 128)
          ? &knope[(size_t)(krow0 + row) * 4096 + h * 128 + col]
          : &kro[(size_t)(krow0 + row) * 64 + (col - 128)];
      gload16(src, &kbuf[bsel][s * 512]);
    }
  };
  auto stageV = [&](int kt) {
#pragma unroll
    for (int i = 0; i < 2; ++i) {           // 16 segs of 1KB, 2 per wave
      int s = w * 2 + i;
      int pp = s * 1024 + lane * 16;
      int d = pp >> 7;
      int key = ((pp ^ ((d & 7) << 4)) & 127) >> 1;
      gload16(&vT[(size_t)(bh * 128 + d) * 2048 + kt * 64 + key], &vbuf[s * 512]);
    }
  };

  stageK(0, 0);
  int cur = 0;
  for (int kt = 0; kt < nkt; ++kt) {
    // top barrier: K[kt] landed; all waves' prior PV reads of vbuf done
    asm volatile("s_waitcnt vmcnt(0)" ::: "memory");
    barrier_raw();
    stageV(kt);                              // 2 loads/wave (oldest)
    if (kt + 1 < nkt) stageK(kt + 1, cur ^ 1);  // 3 loads/wave, survive mid barrier
    const char* kb = (const char*)kbuf[cur];

    // swapped QK^T: sacc[nb] = K_block(nb) x Q -> P^T fragments
    f4v sacc[4];
    __builtin_amdgcn_s_setprio(1);
#pragma unroll
    for (int nb = 0; nb < 4; ++nb) {
      sacc[nb] = f4v{0.f, 0.f, 0.f, 0.f};
      const int row = nb * 16 + l15;        // key row in kbuf
      const int sw = (row & 7) << 4;
#pragma unroll
      for (int kc = 0; kc < 6; ++kc) {
        s8v kf = *reinterpret_cast<const s8v*>(kb + row * 384 + ((kc * 64 + l4 * 16) ^ sw));
        sacc[nb] = mfma16(kf, qf[kc], sacc[nb]);   // A=K, B=Q
      }
    }
    __builtin_amdgcn_s_setprio(0);

    // scale (exp2 space) + causal mask: sacc[nb][j] = S[q=myq][key]
#pragma unroll
    for (int nb = 0; nb < 4; ++nb) {
      int key = kt * 64 + nb * 16 + 4 * l4;
#pragma unroll
      for (int j = 0; j < 4; ++j) {
        float sv = sacc[nb][j] * sc2;
        if (kt >= 2 * qt && key + j > myq) sv = -INFINITY;
        sacc[nb][j] = sv;
      }
    }
    // row max: 16 in-lane + 4 lanes (l4 groups) via shfl_xor 16,32
    float mx = sacc[0][0];
#pragma unroll
    for (int nb = 0; nb < 4; ++nb)
#pragma unroll
      for (int j = 0; j < 4; ++j) mx = fmaxf(mx, sacc[nb][j]);
    mx = fmaxf(mx, __shfl_xor(mx, 16));
    mx = fmaxf(mx, __shfl_xor(mx, 32));

    // T13 defer-max (scalar)
    if (!__all(mx - m_r <= 8.0f)) {
      float mnew = fmaxf(m_r, mx);
      float al = exp2f(m_r - mnew);
      m_r = mnew;
      l_r *= al;
      float alj[4];
#pragma unroll
      for (int j = 0; j < 4; ++j) alj[j] = __shfl(al, 4 * l4 + j);  // al of q=w*16+4*l4+j
#pragma unroll
      for (int nv = 0; nv < 8; ++nv)
#pragma unroll
        for (int j = 0; j < 4; ++j) oacc[nv][j] *= alj[j];
    }
    // P = exp2(s - m), row-sum
    float rs = 0.f;
#pragma unroll
    for (int nb = 0; nb < 4; ++nb)
#pragma unroll
      for (int j = 0; j < 4; ++j) {
        float pv = exp2f(sacc[nb][j] - m_r);
        sacc[nb][j] = pv;
        rs += pv;
      }
    rs += __shfl_xor(rs, 16);
    rs += __shfl_xor(rs, 32);
    l_r += rs;

    // P -> PV A-fragments in-register:
    // target frag(kc2) elem i = P[q=l15][k=32*kc2+8*l4+i]; source lane
    // l4_s=2*(l4&1)+(i>>2), reg nb_s=2*kc2+(l4>>1), j_s=i&3.
    uint pkE[4], pkO[4];
#pragma unroll
    for (int nb = 0; nb < 4; ++nb) {
      pkE[nb] = ((uint)f2b(sacc[nb][1]) << 16) | f2b(sacc[nb][0]);
      pkO[nb] = ((uint)f2b(sacc[nb][3]) << 16) | f2b(sacc[nb][2]);
    }
    const int hi2 = l4 >> 1;
    const int sbase = l15 + 16 * (2 * (l4 & 1));
    union PF { uint u[4]; s8v v; } pf0, pf1;
#pragma unroll
    for (int t = 0; t < 4; ++t) {
      int src = sbase + 16 * (t >> 1);
      uint wa0 = __shfl((t & 1) ? pkO[0] : pkE[0], src);
      uint wb0 = __shfl((t & 1) ? pkO[1] : pkE[1], src);
      pf0.u[t] = hi2 ? wb0 : wa0;
      uint wa1 = __shfl((t & 1) ? pkO[2] : pkE[2], src);
      uint wb1 = __shfl((t & 1) ? pkO[3] : pkE[3], src);
      pf1.u[t] = hi2 ? wb1 : wa1;
    }

    // mid barrier: V[kt] landed (counted: K[kt+1]'s 3 loads stay outstanding)
    if (kt + 1 < nkt) {
      asm volatile("s_waitcnt vmcnt(3)" ::: "memory");
    } else {
      asm volatile("s_waitcnt vmcnt(0)" ::: "memory");
    }
    barrier_raw();

    // O += P V
    const char* vb = (const char*)vbuf;
    __builtin_amdgcn_s_setprio(1);
#pragma unroll
    for (int kc2 = 0; kc2 < 2; ++kc2) {
      s8v pfr = kc2 ? pf1.v : pf0.v;
#pragma unroll
      for (int nv = 0; nv < 8; ++nv) {
        const int d = nv * 16 + l15;
        s8v vf = *reinterpret_cast<const s8v*>(vb + d * 128 + ((kc2 * 64 + l4 * 16) ^ ((d & 7) << 4)));
        oacc[nv] = mfma16(pfr, vf, oacc[nv]);
      }
    }
    __builtin_amdgcn_s_setprio(0);
    cur ^= 1;
  }

  // epilogue: normalize + store; inv for q=w*16+4*l4+j from lane 4*l4+j
  float invl = 1.0f / l_r;
  float invj[4];
#pragma unroll
  for (int j = 0; j < 4; ++j) invj[j] = __shfl(invl, 4 * l4 + j);
#pragma unroll
  for (int j = 0; j < 4; ++j) {
    int m = b * 2048 + qt * 128 + w * 16 + 4 * l4 + j;
#pragma unroll
    for (int nv = 0; nv < 8; ++nv)
      out[(size_t)m * 2048 + h * 128 + nv * 16 + l15] = f2b(oacc[nv][j] * invj[j]);
  }
}

// ---------------------------------------------------------------- launch
// Workspace layout (lifetime-aliased, peak 96.5 MiB):
//   [ 0,32M)  g2kv   overlay: g1 fp32 18M
//   [32,56M)  g2q    overlay: xbf 16M @32M, w1 4.5M @48M
//   [56,72M)  vT     overlay: nq 4M @56M, nkv 4M @60M, w2q 3M @64M, w2kv 4M @67M
//   [72,88M)  att
//   [88,96M)  wpj
//   [96,96.5M) kro
extern "C" void kernel_launch(void* const* d_in, const int* in_sizes, int n_in,
                              void* d_out, int out_size, void* d_ws, size_t ws_size,
                              hipStream_t stream) {
  const float* x       = (const float*)d_in[0];
  const float* freqs   = (const float*)d_in[2];
  const float* w_cq    = (const float*)d_in[3];
  const float* w_qnorm = (const float*)d_in[4];
  const float* w_dqn   = (const float*)d_in[5];
  const float* w_dqr   = (const float*)d_in[6];
  const float* w_ckv   = (const float*)d_in[7];
  const float* w_kvnorm= (const float*)d_in[8];
  const float* w_dkn   = (const float*)d_in[9];
  const float* w_dv    = (const float*)d_in[10];
  const float* w_krope = (const float*)d_in[11];
  const float* w_proj  = (const float*)d_in[12];
  float* out = (float*)d_out;

  char* ws = (char*)d_ws;
  const size_t MB = 1ull << 20;
  ushort* g2kv = (ushort*)(ws + 0);
  float*  g1   = (float*) (ws + 0);
  ushort* g2q  = (ushort*)(ws + 32 * MB);
  ushort* xbf  = (ushort*)(ws + 32 * MB);
  ushort* w1   = (ushort*)(ws + 48 * MB);
  ushort* vT   = (ushort*)(ws + 56 * MB);
  ushort* nq   = (ushort*)(ws + 56 * MB);
  ushort* nkv  = (ushort*)(ws + 60 * MB);
  ushort* w2q  = (ushort*)(ws + 64 * MB);
  ushort* w2kv = (ushort*)(ws + 67 * MB);
  ushort* att  = (ushort*)(ws + 72 * MB);
  ushort* wpj  = (ushort*)(ws + 88 * MB);
  ushort* kro  = (ushort*)(ws + 96 * MB);

  // one cast launch for everything (src=nullptr => zero-fill)
  CastTab t;
  const float* srcs[10] = {x, w_cq, w_ckv, w_krope, nullptr,
                           w_dqn, w_dqr, w_dkn, w_dv, w_proj};
  ushort* dsts[10] = {xbf, w1, w1 + 512 * 2048, w1 + 1024 * 2048, w1 + 1088 * 2048,
                      w2q, w2q + 2048 * 512, w2kv, w2kv + 2048 * 512, wpj};
  int ns[10] = {4096 * 2048, 512 * 2048, 512 * 2048, 64 * 2048, 64 * 2048,
                2048 * 512, 1024 * 512, 2048 * 512, 2048 * 512, 2048 * 2048};
  int blk = 0;
  for (int i = 0; i < 10; ++i) {
    t.seg[i].src = srcs[i];
    t.seg[i].dst = dsts[i];
    t.seg[i].n4 = ns[i] / 4;
    t.seg[i].blk0 = blk;
    blk += (ns[i] / 4 + 255) / 256;
  }
  cast_all_kernel<<<blk, 256, 0, stream>>>(t);

  // fused compress GEMM  [cq | ckv | krope]
  gemm_bt<false><<<dim3(32, 9), 256, 0, stream>>>(xbf, w1, g1, 1152, 2048);
  // RMSNorm + k_rope RoPE
  norm_rope1_kernel<<<4096, 256, 0, stream>>>(g1, w_qnorm, w_kvnorm, freqs, nq, nkv, kro);
  // Q + KV decompress, one launch
  gemm2_dual<<<dim3(32, 56), 256, 0, stream>>>(nq, w2q, g2q, nkv, w2kv, g2kv);
  // V transpose + Q RoPE, one launch
  misc_fused_kernel<<<2048 + 8192, 256, 0, stream>>>(g2q, freqs, g2kv, vT);
  // causal flash attention
  attn_kernel<<<512, 512, 0, stream>>>(g2q, g2kv, kro, vT, att);
  // output projection
  gemm_bt<false><<<dim3(32, 16), 256, 0, stream>>>(att, wpj, out, 2048, 2048);
}